// Round 1
// baseline (72.151 us; speedup 1.0000x reference)
//
#include <hip/hip_runtime.h>

#define B_   4
#define NC_  128
#define NM_  16384
#define OUTROW 1700
#define FACTORF ((float)(27.2114 * 0.529177249))

__device__ __forceinline__ float fast_tanh(float x) {
    float e = __expf(2.0f * x);
    return 1.0f - 2.0f * __builtin_amdgcn_rcpf(e + 1.0f);
}

// ---------------------------------------------------------------------------
// Kernel 0: detect whether real_mask is byte-packed (bool) or int32.
// Reads first 16384 words (= 64KB, safe under both interpretations).
// Random 0/1 bytes give words >1 almost surely; int32 mask gives only 0/1.
__global__ __launch_bounds__(256) void k_detect(const unsigned* __restrict__ mask,
                                                int* __restrict__ flag) {
    __shared__ int s;
    if (threadIdx.x == 0) s = 0;
    __syncthreads();
    int bad = 0;
    for (int i = threadIdx.x; i < NM_; i += 256) bad |= (mask[i] > 1u) ? 1 : 0;
    if (bad) atomicOr(&s, 1);
    __syncthreads();
    if (threadIdx.x == 0) *flag = s;
}

// ---------------------------------------------------------------------------
// Kernel 1: esp + efield accumulation over NM charges, fused with the esp MLP.
// One block per (b, 2-atom tile). 256 threads.
__global__ __launch_bounds__(256) void k_esp(
    const float* __restrict__ atom_coords, const float* __restrict__ charge_coords,
    const float* __restrict__ charges, const void* __restrict__ mask,
    const int* __restrict__ flagp,
    const float* __restrict__ eW0, const float* __restrict__ eb0,
    const float* __restrict__ eW1, const float* __restrict__ eb1,
    const float* __restrict__ eW2, const float* __restrict__ eb2,
    const int* __restrict__ atom_types,
    float* __restrict__ efield_ws, float* __restrict__ out)
{
    const int t   = threadIdx.x;
    const int blk = blockIdx.x;
    const int b   = blk >> 6;
    const int n0  = (blk & 63) * 2;
    const int byteMask = *flagp;

    float ax0, ay0, az0, ax1, ay1, az1;
    {
        const float* p0 = atom_coords + (size_t)(b * NC_ + n0) * 3;
        ax0 = p0[0]; ay0 = p0[1]; az0 = p0[2];
        ax1 = p0[3]; ay1 = p0[4]; az1 = p0[5];
    }
    float acc[8];
#pragma unroll
    for (int v = 0; v < 8; ++v) acc[v] = 0.0f;

    const float* ccb = charge_coords + (size_t)b * NM_ * 3;
    const float* chb = charges + (size_t)b * NM_;
    const unsigned char* mb8 = (const unsigned char*)mask + (size_t)b * NM_;
    const int* mb32 = (const int*)mask + (size_t)b * NM_;

    for (int m = t; m < NM_; m += 256) {
        float cx = ccb[3 * m + 0], cy = ccb[3 * m + 1], cz = ccb[3 * m + 2];
        int mk = byteMask ? (int)mb8[m] : mb32[m];
        float q = mk ? chb[m] : 0.0f;
        {
            float dx = ax0 - cx, dy = ay0 - cy, dz = az0 - cz;
            float d2 = dx * dx + dy * dy + dz * dz;
            float inv = __builtin_amdgcn_rsqf(d2);
            float inv3 = inv * inv * inv;
            float qi3 = q * inv3;
            acc[0] += q * inv;
            acc[1] += qi3 * dx; acc[2] += qi3 * dy; acc[3] += qi3 * dz;
        }
        {
            float dx = ax1 - cx, dy = ay1 - cy, dz = az1 - cz;
            float d2 = dx * dx + dy * dy + dz * dz;
            float inv = __builtin_amdgcn_rsqf(d2);
            float inv3 = inv * inv * inv;
            float qi3 = q * inv3;
            acc[4] += q * inv;
            acc[5] += qi3 * dx; acc[6] += qi3 * dy; acc[7] += qi3 * dz;
        }
    }
    // wave reduce (64 lanes)
#pragma unroll
    for (int v = 0; v < 8; ++v) {
        float s = acc[v];
#pragma unroll
        for (int off = 32; off > 0; off >>= 1) s += __shfl_xor(s, off, 64);
        acc[v] = s;
    }
    __shared__ float wsum[4][8];
    __shared__ float finals[2][4];   // [atom][esp,fx,fy,fz]
    const int wv = t >> 6;
    if ((t & 63) == 0) {
#pragma unroll
        for (int v = 0; v < 8; ++v) wsum[wv][v] = acc[v];
    }
    __syncthreads();
    if (t < 8) {
        finals[t >> 2][t & 3] = (wsum[0][t] + wsum[1][t] + wsum[2][t] + wsum[3][t]) * FACTORF;
    }
    __syncthreads();
    if (t < 6) {
        int a = t / 3, d = t - 3 * a;
        efield_ws[(size_t)(b * NC_ + n0 + a) * 3 + d] = finals[a][1 + d];
    }
    // ---- esp MLP: 2 atoms x 64 lanes ----
    __shared__ float h0[2][28];
    __shared__ float h1[2][52];
    const int aa = (t >> 6) & 1;
    const int lane = t & 63;
    int cA = 0; float xA = 0.0f;
    if (t < 128) { cA = atom_types[n0 + aa]; xA = finals[aa][0]; }
    if (t < 128 && lane < 25) {
        h0[aa][lane] = fast_tanh(eW0[cA * 25 + lane] * xA + eb0[cA * 25 + lane]);
    }
    __syncthreads();
    if (t < 128 && lane < 50) {
        float s = eb1[cA * 50 + lane];
        const float* wr = eW1 + (size_t)(cA * 50 + lane) * 25;
#pragma unroll
        for (int l = 0; l < 25; ++l) s += wr[l] * h0[aa][l];
        h1[aa][lane] = fast_tanh(s) + h0[aa][lane % 25];
    }
    __syncthreads();
    if (t < 128) {
        float* orow = out + (size_t)(b * NC_ + n0 + aa) * OUTROW;
        for (int kk = lane; kk < 100; kk += 64) {
            float s = eb2[cA * 100 + kk];
            const float* wr = eW2 + (size_t)(cA * 100 + kk) * 50;
#pragma unroll
            for (int l = 0; l < 50; ++l) s += wr[l] * h1[aa][l];
            orow[kk] = fast_tanh(s) + h1[aa][kk % 50];
        }
    }
}

// ---------------------------------------------------------------------------
// Kernel 2: ef MLP stack (127 neighbor rows per atom) + Gram matrix.
// One block per (b,n). 256 threads = 4 waves.
__global__ __launch_bounds__(256, 2) void k_ef(
    const float* __restrict__ atom_coords, const float* __restrict__ efield_ws,
    const int* __restrict__ atom_types,
    const float* __restrict__ fW0, const float* __restrict__ fb0,
    const float* __restrict__ fW1, const float* __restrict__ fb1,
    const float* __restrict__ fW2, const float* __restrict__ fb2,
    float* __restrict__ out)
{
    const int t   = threadIdx.x;
    const int blk = blockIdx.x;
    const int b   = blk >> 7;
    const int n   = blk & 127;

    __shared__ float cst[NC_][3];
    __shared__ float proj[128];
    __shared__ int   cl[128];
    __shared__ int   sidx[128];
    __shared__ int   sc[128];
    __shared__ int   basep[8];
    __shared__ float a0s[6][25];
    __shared__ float b0s[6][25];
    __shared__ float b1s[6][50];
    __shared__ float b2s[6][100];
    __shared__ __align__(16) float w1s[6][50][28];   // 33600 B (Gtmp overlays this)
    __shared__ __align__(16) float y1s[127][52];     // sorted-row y1

    float (*Gtmp)[100][16] = reinterpret_cast<float (*)[100][16]>(&w1s[0][0][0]);

    const int tn = atom_types[n];
    const int c0 = tn * 6;

    // ---- stage ----
    for (int idx = t; idx < NC_ * 3; idx += 256)
        (&cst[0][0])[idx] = atom_coords[(size_t)b * NC_ * 3 + idx];
    for (int idx = t; idx < 150; idx += 256) {
        (&a0s[0][0])[idx] = fW0[c0 * 25 + idx];
        (&b0s[0][0])[idx] = fb0[c0 * 25 + idx];
    }
    for (int idx = t; idx < 300; idx += 256) (&b1s[0][0])[idx] = fb1[c0 * 50 + idx];
    for (int idx = t; idx < 600; idx += 256) (&b2s[0][0])[idx] = fb2[c0 * 100 + idx];
    for (int idx = t; idx < 7500; idx += 256) {
        int c_ = idx / 1250;
        int rem = idx - 1250 * c_;
        int k = rem / 25;
        int l = rem - 25 * k;
        w1s[c_][k][l] = fW1[c0 * 1250 + idx];
    }
    const float efx = efield_ws[(size_t)(b * NC_ + n) * 3 + 0];
    const float efy = efield_ws[(size_t)(b * NC_ + n) * 3 + 1];
    const float efz = efield_ws[(size_t)(b * NC_ + n) * 3 + 2];
    __syncthreads();

    // ---- P0: proj + channel ----
    if (t < 127) {
        int jn = (t < n) ? t : t + 1;
        float rx = cst[n][0] - cst[jn][0];
        float ry = cst[n][1] - cst[jn][1];
        float rz = cst[n][2] - cst[jn][2];
        float d2 = rx * rx + ry * ry + rz * rz;
        proj[t] = (rx * efx + ry * efy + rz * efz) / d2;
        cl[t] = atom_types[jn];
    }
    __syncthreads();
    if (t < 7) {
        int s = 0;
        for (int j = 0; j < 127; ++j) s += (cl[j] < t) ? 1 : 0;
        basep[t] = s;
    }
    __syncthreads();
    if (t < 127) {
        int myc = cl[t];
        int pos = basep[myc];
        for (int j = 0; j < t; ++j) pos += (cl[j] == myc) ? 1 : 0;
        sidx[pos] = t; sc[pos] = myc;
    }
    __syncthreads();

    // ---- P1: layer0 + layer1 for all rows (2 threads per row) ----
    {
        int r = t >> 1, h = t & 1;
        if (r < 127) {
            int c = sc[r];
            float x = proj[sidx[r]];
            float y0[25];
#pragma unroll
            for (int k = 0; k < 25; ++k) y0[k] = fast_tanh(a0s[c][k] * x + b0s[c][k]);
            int kbase = h * 25;
#pragma unroll
            for (int kk = 0; kk < 25; ++kk) {
                int k = kbase + kk;
                float s = b1s[c][k];
                const float4* wrow = (const float4*)&w1s[c][k][0];
#pragma unroll
                for (int l4 = 0; l4 < 6; ++l4) {
                    float4 w = wrow[l4];
                    s += w.x * y0[l4 * 4 + 0] + w.y * y0[l4 * 4 + 1]
                       + w.z * y0[l4 * 4 + 2] + w.w * y0[l4 * 4 + 3];
                }
                s += w1s[c][k][24] * y0[24];
                y1s[r][k] = fast_tanh(s) + y0[kk];
            }
        }
    }
    __syncthreads();

    // ---- P2: layer2 + Gram. Lane L<50 owns neurons L and L+50; waves split p mod 4.
    const int wv = t >> 6;
    const int L  = t & 63;
    float G0[16], G1[16];
#pragma unroll
    for (int a = 0; a < 16; ++a) { G0[a] = 0.0f; G1[a] = 0.0f; }
    float w0r[50], w1r[50];
#pragma unroll 1
    for (int c = 0; c < 6; ++c) {
        const int pbeg = basep[c], pend = basep[c + 1];
        if (pbeg == pend) continue;
        float bb0 = 0.0f, bb1 = 0.0f;
        if (L < 50) {
            const float* Wb = fW2 + (size_t)(c0 + c) * 5000;
            const float2* r0 = (const float2*)(Wb + L * 50);
            const float2* r1 = (const float2*)(Wb + (L + 50) * 50);
#pragma unroll
            for (int j = 0; j < 25; ++j) {
                float2 u = r0[j]; w0r[2 * j] = u.x; w0r[2 * j + 1] = u.y;
                float2 v = r1[j]; w1r[2 * j] = v.x; w1r[2 * j + 1] = v.y;
            }
            bb0 = b2s[c][L]; bb1 = b2s[c][L + 50];
        }
        for (int p = pbeg + wv; p < pend; p += 4) {
            if (L < 50) {
                const float4* yrow = (const float4*)&y1s[p][0];
                float s00 = 0, s01 = 0, s02 = 0, s03 = 0;
                float s10 = 0, s11 = 0, s12 = 0, s13 = 0;
#pragma unroll
                for (int l4 = 0; l4 < 12; ++l4) {
                    float4 y = yrow[l4];
                    s00 += w0r[4 * l4 + 0] * y.x; s01 += w0r[4 * l4 + 1] * y.y;
                    s02 += w0r[4 * l4 + 2] * y.z; s03 += w0r[4 * l4 + 3] * y.w;
                    s10 += w1r[4 * l4 + 0] * y.x; s11 += w1r[4 * l4 + 1] * y.y;
                    s12 += w1r[4 * l4 + 2] * y.z; s13 += w1r[4 * l4 + 3] * y.w;
                }
                float ya = y1s[p][48], yb = y1s[p][49];
                s00 += w0r[48] * ya; s01 += w0r[49] * yb;
                s10 += w1r[48] * ya; s11 += w1r[49] * yb;
                float yres = y1s[p][L];
                float y20 = fast_tanh(s00 + s01 + s02 + s03 + bb0) + yres;
                float y21 = fast_tanh(s10 + s11 + s12 + s13 + bb1) + yres;
#pragma unroll
                for (int a = 0; a < 16; ++a) {
                    float va = __uint_as_float(
                        __builtin_amdgcn_readlane(__float_as_uint(y20), a));
                    G0[a] += y20 * va;
                    G1[a] += y21 * va;
                }
            }
        }
    }
    __syncthreads();   // all P1/P2 uses of w1s & p-loops done; safe to overlay Gtmp
    if (L < 50) {
#pragma unroll
        for (int a = 0; a < 16; ++a) {
            Gtmp[wv][L][a] = G0[a];
            Gtmp[wv][L + 50][a] = G1[a];
        }
    }
    __syncthreads();
    float* orow = out + (size_t)(b * NC_ + n) * OUTROW + 100;
    for (int o = t; o < 1600; o += 256) {
        int k = o >> 4, a = o & 15;
        orow[o] = 2.0f * (Gtmp[0][k][a] + Gtmp[1][k][a] + Gtmp[2][k][a] + Gtmp[3][k][a]);
    }
}

// ---------------------------------------------------------------------------
extern "C" void kernel_launch(void* const* d_in, const int* in_sizes, int n_in,
                              void* d_out, int out_size, void* d_ws, size_t ws_size,
                              hipStream_t stream) {
    (void)in_sizes; (void)n_in; (void)out_size; (void)ws_size;
    const float* atom_coords   = (const float*)d_in[0];
    const float* charge_coords = (const float*)d_in[1];
    const float* charges       = (const float*)d_in[2];
    const float* eW0 = (const float*)d_in[3];
    const float* eb0 = (const float*)d_in[4];
    const float* eW1 = (const float*)d_in[5];
    const float* eb1 = (const float*)d_in[6];
    const float* eW2 = (const float*)d_in[7];
    const float* eb2 = (const float*)d_in[8];
    const float* fW0 = (const float*)d_in[9];
    const float* fb0 = (const float*)d_in[10];
    const float* fW1 = (const float*)d_in[11];
    const float* fb1 = (const float*)d_in[12];
    const float* fW2 = (const float*)d_in[13];
    const float* fb2 = (const float*)d_in[14];
    const int*   atom_types = (const int*)d_in[15];
    const void*  mask = d_in[16];
    float* out = (float*)d_out;

    int*   flag      = (int*)d_ws;
    float* efield_ws = (float*)((char*)d_ws + 64);

    k_detect<<<1, 256, 0, stream>>>((const unsigned*)mask, flag);
    k_esp<<<B_ * (NC_ / 2), 256, 0, stream>>>(
        atom_coords, charge_coords, charges, mask, flag,
        eW0, eb0, eW1, eb1, eW2, eb2, atom_types, efield_ws, out);
    k_ef<<<B_ * NC_, 256, 0, stream>>>(
        atom_coords, efield_ws, atom_types,
        fW0, fb0, fW1, fb1, fW2, fb2, out);
}

// Round 2
// 59.989 us; speedup vs baseline: 1.2027x; 1.2027x over previous
//
#include <hip/hip_runtime.h>

#define B_   4
#define NC_  128
#define NM_  16384
#define OUTROW 1700
#define FACTORF ((float)(27.2114 * 0.529177249))

typedef __attribute__((ext_vector_type(2))) float f32x2;

__device__ __forceinline__ float fast_tanh(float x) {
    float e = __expf(2.0f * x);
    return 1.0f - 2.0f * __builtin_amdgcn_rcpf(e + 1.0f);
}
__device__ __forceinline__ f32x2 mk2(float a, float b) { f32x2 r; r.x = a; r.y = b; return r; }

// ---------------------------------------------------------------------------
// Kernel 0: detect byte-packed (bool) vs int32 mask. Scans all 64KB (byte view).
__global__ __launch_bounds__(256) void k_detect(const uint4* __restrict__ mask,
                                                int* __restrict__ flag) {
    __shared__ int s;
    if (threadIdx.x == 0) s = 0;
    __syncthreads();
    int bad = 0;
    for (int i = threadIdx.x; i < NM_ / 4; i += 256) {
        uint4 v = mask[i];
        bad |= (v.x > 1u) | (v.y > 1u) | (v.z > 1u) | (v.w > 1u);
    }
    if (bad) atomicOr(&s, 1);
    __syncthreads();
    if (threadIdx.x == 0) *flag = s;
}

// ---------------------------------------------------------------------------
// Kernel 1: esp/efield partial sums. Block (b, chunk): chunk of NM_/nchunk
// charges vs all 128 atoms. Thread t: atom a=t&127, half h=t>>7.
// Wave-uniform LDS broadcast reads; deterministic partials to ws.
__global__ __launch_bounds__(256) void k_esp(
    const float* __restrict__ atom_coords, const float* __restrict__ charge_coords,
    const float* __restrict__ charges, const void* __restrict__ mask,
    const int* __restrict__ flagp, float4* __restrict__ partial, int nchunk)
{
    const int t  = threadIdx.x;
    const int b  = blockIdx.x / nchunk;
    const int ch = blockIdx.x % nchunk;
    const int chunkM = NM_ / nchunk;
    const int a = t & 127;
    const int h = t >> 7;
    const int byteMask = *flagp;

    __shared__ float4 stg[256];
    __shared__ float4 psum[128];

    float ax, ay, az;
    {
        const float* p = atom_coords + (size_t)(b * NC_ + a) * 3;
        ax = p[0]; ay = p[1]; az = p[2];
    }
    const float* ccb = charge_coords + (size_t)b * NM_ * 3;
    const float* chb = charges + (size_t)b * NM_;
    const unsigned char* mb8 = (const unsigned char*)mask + (size_t)b * NM_;
    const int* mb32 = (const int*)mask + (size_t)b * NM_;

    float s0 = 0.0f, s1 = 0.0f, s2 = 0.0f, s3 = 0.0f;

    for (int tb = 0; tb < chunkM; tb += 256) {
        int m = ch * chunkM + tb + t;
        float cx = ccb[3 * m + 0], cy = ccb[3 * m + 1], cz = ccb[3 * m + 2];
        int mk = byteMask ? (int)mb8[m] : mb32[m];
        float q = mk ? chb[m] : 0.0f;
        stg[t] = make_float4(cx, cy, cz, q);
        __syncthreads();
        const float4* sp = stg + h * 128;
#pragma unroll 8
        for (int i = 0; i < 128; ++i) {
            float4 cq = sp[i];
            float dx = ax - cq.x, dy = ay - cq.y, dz = az - cq.z;
            float d2 = dx * dx + dy * dy + dz * dz;
            float inv = __builtin_amdgcn_rsqf(d2);
            float inv3 = inv * inv * inv;
            float qi  = cq.w * inv;
            float qi3 = cq.w * inv3;
            s0 += qi;
            s1 += qi3 * dx; s2 += qi3 * dy; s3 += qi3 * dz;
        }
        __syncthreads();
    }
    if (h == 1) psum[a] = make_float4(s0, s1, s2, s3);
    __syncthreads();
    if (h == 0) {
        float4 o = psum[a];
        partial[(size_t)(b * NC_ + a) * nchunk + ch] =
            make_float4(s0 + o.x, s1 + o.y, s2 + o.z, s3 + o.w);
    }
}

// ---------------------------------------------------------------------------
// Kernel 2: partial reduction + esp MLP + ef MLP stack + Gram. Block (b,n).
__global__ __launch_bounds__(256, 2) void k_ef(
    const float* __restrict__ atom_coords, const float4* __restrict__ partial, int nchunk,
    const int* __restrict__ atom_types,
    const float* __restrict__ eW0, const float* __restrict__ eb0,
    const float* __restrict__ eW1, const float* __restrict__ eb1,
    const float* __restrict__ eW2, const float* __restrict__ eb2,
    const float* __restrict__ fW0, const float* __restrict__ fb0,
    const float* __restrict__ fW1, const float* __restrict__ fb1,
    const float* __restrict__ fW2, const float* __restrict__ fb2,
    float* __restrict__ out)
{
    const int t   = threadIdx.x;
    const int blk = blockIdx.x;
    const int b   = blk >> 7;
    const int n   = blk & 127;

    __shared__ float cst[NC_][3];
    __shared__ float proj[128];
    __shared__ int   cl[128];
    __shared__ int   sidx[128];
    __shared__ int   sc[128];
    __shared__ int   basep[8];
    __shared__ float a0s[6][25];
    __shared__ float b0s[6][25];
    __shared__ float b1s[6][50];
    __shared__ float b2s[6][100];
    __shared__ float espf[4];
    __shared__ float h0e[25];
    __shared__ float h1e[52];
    __shared__ __align__(16) float w1s[6][50][28];   // 33600 B; Gtmp overlays after P1
    __shared__ __align__(16) float y1s[127][52];
    __shared__ __align__(16) float y2a[127][16];

    float (*Gtmp)[100][16] = reinterpret_cast<float (*)[100][16]>(&w1s[0][0][0]);

    const int tn = atom_types[n];
    const int c0 = tn * 6;

    // ---- stage (all waves) ----
    for (int idx = t; idx < NC_ * 3; idx += 256)
        (&cst[0][0])[idx] = atom_coords[(size_t)b * NC_ * 3 + idx];
    for (int idx = t; idx < 150; idx += 256) {
        (&a0s[0][0])[idx] = fW0[c0 * 25 + idx];
        (&b0s[0][0])[idx] = fb0[c0 * 25 + idx];
    }
    for (int idx = t; idx < 300; idx += 256) (&b1s[0][0])[idx] = fb1[c0 * 50 + idx];
    for (int idx = t; idx < 600; idx += 256) (&b2s[0][0])[idx] = fb2[c0 * 100 + idx];
    for (int idx = t; idx < 7500; idx += 256) {
        int c_ = idx / 1250;
        int rem = idx - 1250 * c_;
        int k = rem / 25;
        int l = rem - 25 * k;
        w1s[c_][k][l] = fW1[c0 * 1250 + idx];
    }
    // ---- reduce chunk partials (wave 0) ----
    if (t < 64) {
        float4 v = make_float4(0.f, 0.f, 0.f, 0.f);
        if (t < nchunk) v = partial[(size_t)(b * NC_ + n) * nchunk + t];
#pragma unroll
        for (int off = 32; off > 0; off >>= 1) {
            v.x += __shfl_xor(v.x, off, 64);
            v.y += __shfl_xor(v.y, off, 64);
            v.z += __shfl_xor(v.z, off, 64);
            v.w += __shfl_xor(v.w, off, 64);
        }
        if (t == 0) {
            espf[0] = v.x * FACTORF;
            espf[1] = v.y * FACTORF;
            espf[2] = v.z * FACTORF;
            espf[3] = v.w * FACTORF;
        }
    }
    __syncthreads();

    // ---- phase A: proj+channel (t<127)  ||  esp layer0 (t in [128,153)) ----
    if (t < 127) {
        int jn = (t < n) ? t : t + 1;
        float rx = cst[n][0] - cst[jn][0];
        float ry = cst[n][1] - cst[jn][1];
        float rz = cst[n][2] - cst[jn][2];
        float d2 = rx * rx + ry * ry + rz * rz;
        proj[t] = (rx * espf[1] + ry * espf[2] + rz * espf[3]) / d2;
        cl[t] = atom_types[jn];
    } else if (t >= 128 && t < 153) {
        int l = t - 128;
        h0e[l] = fast_tanh(eW0[tn * 25 + l] * espf[0] + eb0[tn * 25 + l]);
    }
    __syncthreads();
    // ---- phase B: basep (t<7)  ||  esp layer1 (t in [128,178)) ----
    if (t < 7) {
        int s = 0;
        for (int j = 0; j < 127; ++j) s += (cl[j] < t) ? 1 : 0;
        basep[t] = s;
    } else if (t >= 128 && t < 178) {
        int l = t - 128;
        float s = eb1[tn * 50 + l];
        const float* wr = eW1 + (size_t)(tn * 50 + l) * 25;
#pragma unroll
        for (int j = 0; j < 25; ++j) s += wr[j] * h0e[j];
        h1e[l] = fast_tanh(s) + h0e[l % 25];
    }
    __syncthreads();
    // ---- phase C: stable sort scatter (t<127)  ||  esp layer2 (t in [128,228)) ----
    if (t < 127) {
        int myc = cl[t];
        int pos = basep[myc];
        for (int j = 0; j < t; ++j) pos += (cl[j] == myc) ? 1 : 0;
        sidx[pos] = t; sc[pos] = myc;
    } else if (t >= 128 && t < 228) {
        int k = t - 128;
        float s = eb2[tn * 100 + k];
        const float* wr = eW2 + (size_t)(tn * 100 + k) * 50;
#pragma unroll
        for (int j = 0; j < 50; ++j) s += wr[j] * h1e[j];
        out[(size_t)(b * NC_ + n) * OUTROW + k] = fast_tanh(s) + h1e[k % 50];
    }
    __syncthreads();

    // ---- P1: layer0 + layer1 for all 127 rows (2 threads per row) ----
    {
        int r = t >> 1, h = t & 1;
        if (r < 127) {
            int c = sc[r];
            float x = proj[sidx[r]];
            float y0[25];
#pragma unroll
            for (int k = 0; k < 25; ++k) y0[k] = fast_tanh(a0s[c][k] * x + b0s[c][k]);
            int kbase = h * 25;
#pragma unroll
            for (int kk = 0; kk < 25; ++kk) {
                int k = kbase + kk;
                float s = b1s[c][k];
                const float4* wrow = (const float4*)&w1s[c][k][0];
#pragma unroll
                for (int l4 = 0; l4 < 6; ++l4) {
                    float4 w = wrow[l4];
                    s += w.x * y0[l4 * 4 + 0] + w.y * y0[l4 * 4 + 1]
                       + w.z * y0[l4 * 4 + 2] + w.w * y0[l4 * 4 + 3];
                }
                s += w1s[c][k][24] * y0[24];
                y1s[r][k] = fast_tanh(s) + y0[kk];
            }
        }
    }
    __syncthreads();

    // ---- P2: layer2 + Gram, two neuron-half passes. Lane L<50 owns neuron
    //      pass*50+L. Waves split rows p mod 4. ~50 weight VGPRs live.
    const int wv = t >> 6;
    const int L  = t & 63;
#pragma unroll 1
    for (int pass = 0; pass < 2; ++pass) {
        f32x2 G2[8];
#pragma unroll
        for (int j = 0; j < 8; ++j) G2[j] = mk2(0.f, 0.f);
#pragma unroll 1
        for (int c = 0; c < 6; ++c) {
            const int pbeg = basep[c], pend = basep[c + 1];
            if (pbeg == pend) continue;
            f32x2 w2r[25];
            float bb = 0.0f;
            if (L < 50) {
                const f32x2* wr = (const f32x2*)(fW2 + (size_t)((c0 + c) * 100 + pass * 50 + L) * 50);
#pragma unroll
                for (int j = 0; j < 25; ++j) w2r[j] = wr[j];
                bb = b2s[c][pass * 50 + L];
            }
            for (int p = pbeg + wv; p < pend; p += 4) {
                if (L < 50) {
                    const float4* y4 = (const float4*)&y1s[p][0];
                    f32x2 acc2 = mk2(0.f, 0.f);
#pragma unroll
                    for (int l4 = 0; l4 < 12; ++l4) {
                        float4 v = y4[l4];
                        acc2 += w2r[2 * l4]     * mk2(v.x, v.y);
                        acc2 += w2r[2 * l4 + 1] * mk2(v.z, v.w);
                    }
                    {
                        f32x2 vt = ((const f32x2*)&y1s[p][0])[24];
                        acc2 += w2r[24] * vt;
                    }
                    float s = acc2.x + acc2.y + bb;
                    float yres = y1s[p][L];
                    float y2 = fast_tanh(s) + yres;
                    if (pass == 0 && L < 16) y2a[p][L] = y2;
                    f32x2 yy = mk2(y2, y2);
                    const f32x2* yap = (const f32x2*)&y2a[p][0];
#pragma unroll
                    for (int j = 0; j < 8; ++j) G2[j] += yy * yap[j];
                }
            }
        }
        __syncthreads();   // pass0: w1s fully dead (post-P1); y2a complete per-wave
        if (L < 50) {
            float2* gp = (float2*)&Gtmp[wv][pass * 50 + L][0];
#pragma unroll
            for (int j = 0; j < 8; ++j) gp[j] = make_float2(G2[j].x, G2[j].y);
        }
    }
    __syncthreads();
    float* orow = out + (size_t)(b * NC_ + n) * OUTROW + 100;
    for (int o = t; o < 1600; o += 256) {
        int k = o >> 4, a = o & 15;
        orow[o] = 2.0f * (Gtmp[0][k][a] + Gtmp[1][k][a] + Gtmp[2][k][a] + Gtmp[3][k][a]);
    }
}

// ---------------------------------------------------------------------------
extern "C" void kernel_launch(void* const* d_in, const int* in_sizes, int n_in,
                              void* d_out, int out_size, void* d_ws, size_t ws_size,
                              hipStream_t stream) {
    (void)in_sizes; (void)n_in; (void)out_size;
    const float* atom_coords   = (const float*)d_in[0];
    const float* charge_coords = (const float*)d_in[1];
    const float* charges       = (const float*)d_in[2];
    const float* eW0 = (const float*)d_in[3];
    const float* eb0 = (const float*)d_in[4];
    const float* eW1 = (const float*)d_in[5];
    const float* eb1 = (const float*)d_in[6];
    const float* eW2 = (const float*)d_in[7];
    const float* eb2 = (const float*)d_in[8];
    const float* fW0 = (const float*)d_in[9];
    const float* fb0 = (const float*)d_in[10];
    const float* fW1 = (const float*)d_in[11];
    const float* fb1 = (const float*)d_in[12];
    const float* fW2 = (const float*)d_in[13];
    const float* fb2 = (const float*)d_in[14];
    const int*   atom_types = (const int*)d_in[15];
    const void*  mask = d_in[16];
    float* out = (float*)d_out;

    // ws layout: [0..255] flag; [256..] float4 partials [B][NC][nchunk]
    int nchunk = 64;
    while (nchunk > 1 && (size_t)(256 + (size_t)B_ * NC_ * nchunk * 16) > ws_size)
        nchunk >>= 1;
    int*    flag    = (int*)d_ws;
    float4* partial = (float4*)((char*)d_ws + 256);

    k_detect<<<1, 256, 0, stream>>>((const uint4*)mask, flag);
    k_esp<<<B_ * nchunk, 256, 0, stream>>>(
        atom_coords, charge_coords, charges, mask, flag, partial, nchunk);
    k_ef<<<B_ * NC_, 256, 0, stream>>>(
        atom_coords, partial, nchunk, atom_types,
        eW0, eb0, eW1, eb1, eW2, eb2,
        fW0, fb0, fW1, fb1, fW2, fb2, out);
}